// Round 6
// baseline (192.990 us; speedup 1.0000x reference)
//
#include <hip/hip_runtime.h>
#include <hip/hip_bf16.h>

// Problem constants: x is [16, 256, 128, 128] float32.
#define B 16
#define C 256
#define H 128
#define W 128
#define HW (H * W)            // 16384
#define BC (B * C)            // 4096
#define KSEL 26               // round(0.1 * 256)

typedef float v4f __attribute__((ext_vector_type(4)));

// ordered-int mapping for monotone binary search over float bits
__device__ __forceinline__ unsigned ordf(float x) {
    unsigned u = __float_as_uint(x);
    return (u & 0x80000000u) ? ~u : (u | 0x80000000u);
}
__device__ __forceinline__ float unordf(unsigned k) {
    unsigned u = (k & 0x80000000u) ? (k & 0x7fffffffu) : ~k;
    return __uint_as_float(u);
}

// -------------------- Kernel 0: derive exact bin thresholds --------------------
// thr[k] = smallest float x in [-2,4] with rintf(tanhf(x)*10.f) >= k, k=0..10.
// Device's own tanhf/rintf -> compare-based binning is bit-identical (monotone).
__global__ void init_thresholds(float* __restrict__ thr) {
    int k = threadIdx.x;
    if (k > 10) return;
    unsigned lo = ordf(-2.0f), hi = ordf(4.0f);
    while (lo < hi) {
        unsigned mid = lo + (hi - lo) / 2;
        float xm = unordf(mid);
        float q = rintf(tanhf(xm) * 10.0f);
        if (q >= (float)k) hi = mid; else lo = mid + 1;
    }
    thr[k] = unordf(lo);
}

// -------------------- Kernel 1: fused per-channel score + copy --------------------
// One block (256 threads) per (b,c). ALL 16 float4 loads issued up-front into
// registers (max MLP), then stores + ballot/stat processing. Histogram via
// ballot+popcount (wave-uniform, scalar-pipe adds).
__global__ __launch_bounds__(256) void score_copy_kernel(const float* __restrict__ x,
                                                         const float* __restrict__ thr,
                                                         double* __restrict__ score,
                                                         float* __restrict__ out) {
    const int bc = blockIdx.x;
    const v4f* xv = (const v4f*)(x + (size_t)bc * HW);
    v4f* ov = (v4f*)(out + (size_t)bc * HW);

    // issue all 16 loads before anything else
    v4f d[16];
#pragma unroll
    for (int ii = 0; ii < 16; ++ii) d[ii] = xv[threadIdx.x + ii * 256];

    float t[11];
#pragma unroll
    for (int k = 0; k < 11; ++k) t[k] = thr[k];

    unsigned cge[11];
#pragma unroll
    for (int k = 0; k < 11; ++k) cge[k] = 0;
    double sum = 0.0, sumsq = 0.0;

#pragma unroll
    for (int ii = 0; ii < 16; ++ii) {
        v4f v = d[ii];
        __builtin_nontemporal_store(v, &ov[threadIdx.x + ii * 256]);
        float s4 = (v.x + v.y) + (v.z + v.w);
        float q4 = fmaf(v.w, v.w, fmaf(v.z, v.z, fmaf(v.y, v.y, v.x * v.x)));
        sum += (double)s4;
        sumsq += (double)q4;
        float arr[4] = {v.x, v.y, v.z, v.w};
#pragma unroll
        for (int j = 0; j < 4; ++j) {
            float f = arr[j];
#pragma unroll
            for (int k = 0; k < 11; ++k)
                cge[k] += (unsigned)__popcll(__ballot(f >= t[k]));
        }
    }

    // cge[] is wave-uniform. Reduce sum/sumsq across the wave.
#pragma unroll
    for (int off = 32; off > 0; off >>= 1) {
        sum += __shfl_down(sum, off);
        sumsq += __shfl_down(sumsq, off);
    }

    __shared__ unsigned sh_cge[4][11];
    __shared__ double sh_sum[4], sh_sq[4];
    const int wave = threadIdx.x >> 6;
    const int lane = threadIdx.x & 63;
    if (lane == 0) {
#pragma unroll
        for (int k = 0; k < 11; ++k) sh_cge[wave][k] = cge[k];
        sh_sum[wave] = sum;
        sh_sq[wave] = sumsq;
    }
    __syncthreads();

    if (threadIdx.x == 0) {
        unsigned g[11];
#pragma unroll
        for (int k = 0; k < 11; ++k)
            g[k] = sh_cge[0][k] + sh_cge[1][k] + sh_cge[2][k] + sh_cge[3][k];
        double s = sh_sum[0] + sh_sum[1] + sh_sum[2] + sh_sum[3];
        double sq = sh_sq[0] + sh_sq[1] + sh_sq[2] + sh_sq[3];

        double ent = 0.0;
        double inv = 1.0 / (double)g[0];
#pragma unroll
        for (int k = 0; k < 11; ++k) {
            unsigned ck = (k < 10) ? (g[k] - g[k + 1]) : g[10];
            double p = (double)ck * inv;
            if (p > 0.0) ent -= p * log(p);
        }
        const double L = (double)HW;
        double var = (sq - s * s / L) / (L - 1.0);
        score[bc] = ent + 2.0 / (var + 1e-7);
    }
}

// -------------------- Kernel 2: top-k selection -> compact index list --------------------
// One block per batch; rank-by-counting with stable-argsort tie semantics.
// rank < KSEL is unique per selected channel -> compact slot.
__global__ __launch_bounds__(256) void select_kernel(const double* __restrict__ score,
                                                     int* __restrict__ compact) {
    __shared__ double s[C];
    const int b = blockIdx.x;
    const int t = threadIdx.x;
    s[t] = score[b * C + t];
    __syncthreads();
    const double mine = s[t];
    int rank = 0;
    for (int j = 0; j < C; ++j) {
        double v = s[j];
        rank += (v > mine) || (v == mine && j < t);
    }
    if (rank < KSEL) compact[b * KSEL + rank] = t;
}

// -------------------- Kernel 3: Laplace rewrite of selected channels --------------------
// Exactly B*KSEL channels; 8 blocks per channel (16 rows each), one barrier.
#define LROWS 16
#define PERCH (H / LROWS)   // 8
__global__ __launch_bounds__(256) void laplace_kernel(const float* __restrict__ x,
                                                      const int* __restrict__ compact,
                                                      float* __restrict__ out) {
    const int blk = blockIdx.x;
    const int b = blk / (KSEL * PERCH);
    const int r0 = blk % (KSEL * PERCH);
    const int slot = r0 / PERCH;
    const int chunk = r0 % PERCH;
    const int c = compact[b * KSEL + slot];
    const size_t base = (size_t)(b * C + c) * HW;
    const float* xc = x + base;
    float* oc = out + base;
    const int h0 = chunk * LROWS;

    __shared__ float tile[LROWS + 2][W];
    for (int i = threadIdx.x; i < (LROWS + 2) * (W / 4); i += 256) {
        int rr = i >> 5;       // / (W/4)
        int cv = i & 31;       // % (W/4)
        int h = h0 - 1 + rr;
        v4f v = (v4f)(0.f);
        if (h >= 0 && h < H) v = ((const v4f*)(xc + h * W))[cv];
        ((v4f*)tile[rr])[cv] = v;
    }
    __syncthreads();

    for (int i = threadIdx.x; i < LROWS * W; i += 256) {
        int rr = i >> 7;          // / W
        int col = i & (W - 1);    // % W
        int tr = rr + 1;
        float cc = tile[tr][col];
        float up = tile[tr - 1][col];
        float dn = tile[tr + 1][col];
        float lf = 0.f, rt = 0.f, ul = 0.f, ur = 0.f, dl = 0.f, dr = 0.f;
        if (col > 0) {
            lf = tile[tr][col - 1];
            ul = tile[tr - 1][col - 1];
            dl = tile[tr + 1][col - 1];
        }
        if (col < W - 1) {
            rt = tile[tr][col + 1];
            ur = tile[tr - 1][col + 1];
            dr = tile[tr + 1][col + 1];
        }
        float res = 8.0f * cc - (up + dn + lf + rt + ul + ur + dl + dr);
        __builtin_nontemporal_store(res, &oc[(h0 + rr) * W + col]);
    }
}

extern "C" void kernel_launch(void* const* d_in, const int* in_sizes, int n_in,
                              void* d_out, int out_size, void* d_ws, size_t ws_size,
                              hipStream_t stream) {
    const float* x = (const float*)d_in[0];
    float* out = (float*)d_out;

    double* scores = (double*)d_ws;                         // 4096 doubles
    int* compact = (int*)(scores + BC);                     // 416 ints
    float* thr = (float*)(compact + B * KSEL);              // 11 floats

    init_thresholds<<<1, 64, 0, stream>>>(thr);
    score_copy_kernel<<<BC, 256, 0, stream>>>(x, thr, scores, out);
    select_kernel<<<B, 256, 0, stream>>>(scores, compact);
    laplace_kernel<<<B * KSEL * PERCH, 256, 0, stream>>>(x, compact, out);
}

// Round 7
// 182.963 us; speedup vs baseline: 1.0548x; 1.0548x over previous
//
#include <hip/hip_runtime.h>
#include <hip/hip_bf16.h>

// Problem constants: x is [16, 256, 128, 128] float32.
#define B 16
#define C 256
#define H 128
#define W 128
#define HW (H * W)            // 16384
#define BC (B * C)            // 4096
#define KSEL 26               // round(0.1 * 256)

typedef float v4f __attribute__((ext_vector_type(4)));

// ordered-int mapping for monotone binary search over float bits
__device__ __forceinline__ unsigned ordf(float x) {
    unsigned u = __float_as_uint(x);
    return (u & 0x80000000u) ? ~u : (u | 0x80000000u);
}
__device__ __forceinline__ float unordf(unsigned k) {
    unsigned u = (k & 0x80000000u) ? (k & 0x7fffffffu) : ~k;
    return __uint_as_float(u);
}

// -------------------- Kernel 1: fused per-channel score + copy --------------------
// One block (256 threads) per (b,c). Depth-4 explicit double-buffered prefetch
// (4 v4f in flight while 4 are processed) -> low VGPR, high MLP. Histogram via
// ballot+popcount (wave-uniform, scalar pipe). Thresholds derived in-block by
// threads 0..10 (binary search over float bits with the device's own
// tanhf/rintf -> binning bit-identical to direct evaluation; tanhf monotone),
// overlapped with the first load group.
__global__ __launch_bounds__(256) void score_copy_kernel(const float* __restrict__ x,
                                                         double* __restrict__ score,
                                                         float* __restrict__ out) {
    const int bc = blockIdx.x;
    const int tid = threadIdx.x;
    const v4f* xv = (const v4f*)(x + (size_t)bc * HW);
    v4f* ov = (v4f*)(out + (size_t)bc * HW);

    // issue first load group before anything else
    v4f c0 = xv[tid];
    v4f c1 = xv[tid + 256];
    v4f c2 = xv[tid + 512];
    v4f c3 = xv[tid + 768];

    // thr[k] = smallest float with rintf(tanhf(x)*10) >= k, k=0..10
    __shared__ float sthr[11];
    if (tid < 11) {
        unsigned lo = ordf(-2.0f), hi = ordf(4.0f);
        while (lo < hi) {
            unsigned mid = lo + (hi - lo) / 2;
            float q = rintf(tanhf(unordf(mid)) * 10.0f);
            if (q >= (float)tid) hi = mid; else lo = mid + 1;
        }
        sthr[tid] = unordf(lo);
    }
    __syncthreads();
    float t[11];
#pragma unroll
    for (int k = 0; k < 11; ++k) t[k] = sthr[k];

    unsigned cge[11];
#pragma unroll
    for (int k = 0; k < 11; ++k) cge[k] = 0;
    double sum = 0.0, sumsq = 0.0;

#define BALLOTS(f)                                                        \
    do {                                                                  \
        float _f = (f);                                                   \
        _Pragma("unroll")                                                 \
        for (int k = 0; k < 11; ++k)                                      \
            cge[k] += (unsigned)__popcll(__ballot(_f >= t[k]));           \
    } while (0)

#define PROCESS(vv, slot)                                                 \
    do {                                                                  \
        __builtin_nontemporal_store(vv, &ov[tid + (slot) * 256]);         \
        ps += (vv.x + vv.y) + (vv.z + vv.w);                              \
        pq = fmaf(vv.w, vv.w, fmaf(vv.z, vv.z,                            \
             fmaf(vv.y, vv.y, fmaf(vv.x, vv.x, pq))));                    \
        BALLOTS(vv.x); BALLOTS(vv.y); BALLOTS(vv.z); BALLOTS(vv.w);       \
    } while (0)

#pragma unroll
    for (int g = 0; g < 4; ++g) {
        v4f n0, n1, n2, n3;
        if (g < 3) {
            const int nb = tid + (g + 1) * 1024;
            n0 = xv[nb];
            n1 = xv[nb + 256];
            n2 = xv[nb + 512];
            n3 = xv[nb + 768];
        }
        float ps = 0.f, pq = 0.f;
        PROCESS(c0, g * 4 + 0);
        PROCESS(c1, g * 4 + 1);
        PROCESS(c2, g * 4 + 2);
        PROCESS(c3, g * 4 + 3);
        sum += (double)ps;
        sumsq += (double)pq;
        if (g < 3) { c0 = n0; c1 = n1; c2 = n2; c3 = n3; }
    }
#undef PROCESS
#undef BALLOTS

    // cge[] is wave-uniform. Reduce sum/sumsq across the wave.
#pragma unroll
    for (int off = 32; off > 0; off >>= 1) {
        sum += __shfl_down(sum, off);
        sumsq += __shfl_down(sumsq, off);
    }

    __shared__ unsigned sh_cge[4][11];
    __shared__ double sh_sum[4], sh_sq[4];
    const int wave = tid >> 6;
    const int lane = tid & 63;
    if (lane == 0) {
#pragma unroll
        for (int k = 0; k < 11; ++k) sh_cge[wave][k] = cge[k];
        sh_sum[wave] = sum;
        sh_sq[wave] = sumsq;
    }
    __syncthreads();

    if (tid == 0) {
        unsigned g[11];
#pragma unroll
        for (int k = 0; k < 11; ++k)
            g[k] = sh_cge[0][k] + sh_cge[1][k] + sh_cge[2][k] + sh_cge[3][k];
        double s = sh_sum[0] + sh_sum[1] + sh_sum[2] + sh_sum[3];
        double sq = sh_sq[0] + sh_sq[1] + sh_sq[2] + sh_sq[3];

        double ent = 0.0;
        double inv = 1.0 / (double)g[0];
#pragma unroll
        for (int k = 0; k < 11; ++k) {
            unsigned ck = (k < 10) ? (g[k] - g[k + 1]) : g[10];
            double p = (double)ck * inv;
            if (p > 0.0) ent -= p * log(p);
        }
        const double L = (double)HW;
        double var = (sq - s * s / L) / (L - 1.0);
        score[bc] = ent + 2.0 / (var + 1e-7);
    }
}

// -------------------- Kernel 2: top-k selection -> compact index list --------------------
// One block per batch; rank-by-counting with stable-argsort tie semantics.
// rank < KSEL is unique per selected channel -> compact slot.
__global__ __launch_bounds__(256) void select_kernel(const double* __restrict__ score,
                                                     int* __restrict__ compact) {
    __shared__ double s[C];
    const int b = blockIdx.x;
    const int t = threadIdx.x;
    s[t] = score[b * C + t];
    __syncthreads();
    const double mine = s[t];
    int rank = 0;
    for (int j = 0; j < C; ++j) {
        double v = s[j];
        rank += (v > mine) || (v == mine && j < t);
    }
    if (rank < KSEL) compact[b * KSEL + rank] = t;
}

// -------------------- Kernel 3: Laplace rewrite of selected channels --------------------
// Exactly B*KSEL channels; 8 blocks per channel (16 rows each), one barrier.
#define LROWS 16
#define PERCH (H / LROWS)   // 8
__global__ __launch_bounds__(256) void laplace_kernel(const float* __restrict__ x,
                                                      const int* __restrict__ compact,
                                                      float* __restrict__ out) {
    const int blk = blockIdx.x;
    const int b = blk / (KSEL * PERCH);
    const int r0 = blk % (KSEL * PERCH);
    const int slot = r0 / PERCH;
    const int chunk = r0 % PERCH;
    const int c = compact[b * KSEL + slot];
    const size_t base = (size_t)(b * C + c) * HW;
    const float* xc = x + base;
    float* oc = out + base;
    const int h0 = chunk * LROWS;

    __shared__ float tile[LROWS + 2][W];
    for (int i = threadIdx.x; i < (LROWS + 2) * (W / 4); i += 256) {
        int rr = i >> 5;       // / (W/4)
        int cv = i & 31;       // % (W/4)
        int h = h0 - 1 + rr;
        v4f v = (v4f)(0.f);
        if (h >= 0 && h < H) v = ((const v4f*)(xc + h * W))[cv];
        ((v4f*)tile[rr])[cv] = v;
    }
    __syncthreads();

    for (int i = threadIdx.x; i < LROWS * W; i += 256) {
        int rr = i >> 7;          // / W
        int col = i & (W - 1);    // % W
        int tr = rr + 1;
        float cc = tile[tr][col];
        float up = tile[tr - 1][col];
        float dn = tile[tr + 1][col];
        float lf = 0.f, rt = 0.f, ul = 0.f, ur = 0.f, dl = 0.f, dr = 0.f;
        if (col > 0) {
            lf = tile[tr][col - 1];
            ul = tile[tr - 1][col - 1];
            dl = tile[tr + 1][col - 1];
        }
        if (col < W - 1) {
            rt = tile[tr][col + 1];
            ur = tile[tr - 1][col + 1];
            dr = tile[tr + 1][col + 1];
        }
        float res = 8.0f * cc - (up + dn + lf + rt + ul + ur + dl + dr);
        __builtin_nontemporal_store(res, &oc[(h0 + rr) * W + col]);
    }
}

extern "C" void kernel_launch(void* const* d_in, const int* in_sizes, int n_in,
                              void* d_out, int out_size, void* d_ws, size_t ws_size,
                              hipStream_t stream) {
    const float* x = (const float*)d_in[0];
    float* out = (float*)d_out;

    double* scores = (double*)d_ws;                         // 4096 doubles
    int* compact = (int*)(scores + BC);                     // 416 ints

    score_copy_kernel<<<BC, 256, 0, stream>>>(x, scores, out);
    select_kernel<<<B, 256, 0, stream>>>(scores, compact);
    laplace_kernel<<<B * KSEL * PERCH, 256, 0, stream>>>(x, compact, out);
}

// Round 8
// 112.813 us; speedup vs baseline: 1.7107x; 1.6218x over previous
//
#include <hip/hip_runtime.h>
#include <hip/hip_bf16.h>

// Problem constants: x is [16, 256, 128, 128] float32.
#define B 16
#define C 256
#define H 128
#define W 128
#define HW (H * W)            // 16384
#define BC (B * C)            // 4096
#define KSEL 26               // round(0.1 * 256)
#define NPART (BC * 2)        // two partial-stat blocks per channel

typedef float v4f __attribute__((ext_vector_type(4)));

// ordered-int mapping for monotone binary search over float bits
__device__ __forceinline__ unsigned ordf(float x) {
    unsigned u = __float_as_uint(x);
    return (u & 0x80000000u) ? ~u : (u | 0x80000000u);
}
__device__ __forceinline__ float unordf(unsigned k) {
    unsigned u = (k & 0x80000000u) ? (k & 0x7fffffffu) : ~k;
    return __uint_as_float(u);
}

// -------------------- Kernel 0: derive exact bin thresholds --------------------
// thr[k] = smallest float x in [-2,4] with rintf(tanhf(x)*10.f) >= k, k=0..10.
// Device's own tanhf/rintf -> compare-based binning is bit-identical (monotone).
__global__ void init_thresholds(float* __restrict__ thr) {
    int k = threadIdx.x;
    if (k > 10) return;
    unsigned lo = ordf(-2.0f), hi = ordf(4.0f);
    while (lo < hi) {
        unsigned mid = lo + (hi - lo) / 2;
        float xm = unordf(mid);
        float q = rintf(tanhf(xm) * 10.0f);
        if (q >= (float)k) hi = mid; else lo = mid + 1;
    }
    thr[k] = unordf(lo);
}

// -------------------- Kernel 1: fused partial score + copy --------------------
// TWO blocks (256 threads each) per channel; each streams 32 KB (8 float4 per
// thread) with the R5-proven simple grid-stride loop (compiler schedules it
// best: VGPR ~40, high occupancy). Emits raw partials {cge[11], sum, sumsq};
// the entropy/var/log epilogue is deferred to select_kernel.
__global__ __launch_bounds__(256) void score_copy_kernel(const float* __restrict__ x,
                                                         const float* __restrict__ thr,
                                                         double* __restrict__ psum,
                                                         double* __restrict__ psq,
                                                         unsigned* __restrict__ pg,
                                                         float* __restrict__ out) {
    const int p = blockIdx.x;      // 0 .. NPART-1
    const int bc = p >> 1;
    const int half = p & 1;
    const int tid = threadIdx.x;
    const v4f* xv = ((const v4f*)(x + (size_t)bc * HW)) + half * (HW / 8);
    v4f* ov = ((v4f*)(out + (size_t)bc * HW)) + half * (HW / 8);

    float t[11];
#pragma unroll
    for (int k = 0; k < 11; ++k) t[k] = thr[k];

    unsigned cge[11];
#pragma unroll
    for (int k = 0; k < 11; ++k) cge[k] = 0;
    double sum = 0.0, sumsq = 0.0;

    for (int i = tid; i < HW / 8; i += 256) {
        v4f v = xv[i];
        __builtin_nontemporal_store(v, &ov[i]);
        float s4 = (v.x + v.y) + (v.z + v.w);
        float q4 = fmaf(v.w, v.w, fmaf(v.z, v.z, fmaf(v.y, v.y, v.x * v.x)));
        sum += (double)s4;
        sumsq += (double)q4;
        float arr[4] = {v.x, v.y, v.z, v.w};
#pragma unroll
        for (int j = 0; j < 4; ++j) {
            float f = arr[j];
#pragma unroll
            for (int k = 0; k < 11; ++k)
                cge[k] += (unsigned)__popcll(__ballot(f >= t[k]));
        }
    }

    // cge[] is wave-uniform. Reduce sum/sumsq across the wave.
#pragma unroll
    for (int off = 32; off > 0; off >>= 1) {
        sum += __shfl_down(sum, off);
        sumsq += __shfl_down(sumsq, off);
    }

    __shared__ unsigned sh_cge[4][11];
    __shared__ double sh_sum[4], sh_sq[4];
    const int wave = tid >> 6;
    const int lane = tid & 63;
    if (lane == 0) {
#pragma unroll
        for (int k = 0; k < 11; ++k) sh_cge[wave][k] = cge[k];
        sh_sum[wave] = sum;
        sh_sq[wave] = sumsq;
    }
    __syncthreads();

    if (tid == 0) {
#pragma unroll
        for (int k = 0; k < 11; ++k)
            pg[p * 11 + k] = sh_cge[0][k] + sh_cge[1][k] + sh_cge[2][k] + sh_cge[3][k];
        psum[p] = sh_sum[0] + sh_sum[1] + sh_sum[2] + sh_sum[3];
        psq[p] = sh_sq[0] + sh_sq[1] + sh_sq[2] + sh_sq[3];
    }
}

// -------------------- Kernel 2: finish scores + top-k -> compact list --------------------
// One block per batch; thread t owns channel t: combine the two partials,
// compute entropy + 2/(var+eps), then rank-by-counting with stable-argsort
// tie semantics. rank < KSEL gives a unique compact slot.
__global__ __launch_bounds__(256) void select_kernel(const double* __restrict__ psum,
                                                     const double* __restrict__ psq,
                                                     const unsigned* __restrict__ pg,
                                                     int* __restrict__ compact) {
    __shared__ double s[C];
    const int b = blockIdx.x;
    const int t = threadIdx.x;
    const int p0 = (b * C + t) * 2;

    unsigned g[11];
#pragma unroll
    for (int k = 0; k < 11; ++k) g[k] = pg[p0 * 11 + k] + pg[(p0 + 1) * 11 + k];
    double sum = psum[p0] + psum[p0 + 1];
    double sq = psq[p0] + psq[p0 + 1];

    double ent = 0.0;
    double inv = 1.0 / (double)g[0];
#pragma unroll
    for (int k = 0; k < 11; ++k) {
        unsigned ck = (k < 10) ? (g[k] - g[k + 1]) : g[10];
        double pk = (double)ck * inv;
        if (pk > 0.0) ent -= pk * log(pk);
    }
    const double L = (double)HW;
    double var = (sq - sum * sum / L) / (L - 1.0);
    s[t] = ent + 2.0 / (var + 1e-7);
    __syncthreads();

    const double mine = s[t];
    int rank = 0;
    for (int j = 0; j < C; ++j) {
        double v = s[j];
        rank += (v > mine) || (v == mine && j < t);
    }
    if (rank < KSEL) compact[b * KSEL + rank] = t;
}

// -------------------- Kernel 3: Laplace rewrite of selected channels --------------------
// Exactly B*KSEL channels; 8 blocks per channel (16 rows each), one barrier.
#define LROWS 16
#define PERCH (H / LROWS)   // 8
__global__ __launch_bounds__(256) void laplace_kernel(const float* __restrict__ x,
                                                      const int* __restrict__ compact,
                                                      float* __restrict__ out) {
    const int blk = blockIdx.x;
    const int b = blk / (KSEL * PERCH);
    const int r0 = blk % (KSEL * PERCH);
    const int slot = r0 / PERCH;
    const int chunk = r0 % PERCH;
    const int c = compact[b * KSEL + slot];
    const size_t base = (size_t)(b * C + c) * HW;
    const float* xc = x + base;
    float* oc = out + base;
    const int h0 = chunk * LROWS;

    __shared__ float tile[LROWS + 2][W];
    for (int i = threadIdx.x; i < (LROWS + 2) * (W / 4); i += 256) {
        int rr = i >> 5;       // / (W/4)
        int cv = i & 31;       // % (W/4)
        int h = h0 - 1 + rr;
        v4f v = (v4f)(0.f);
        if (h >= 0 && h < H) v = ((const v4f*)(xc + h * W))[cv];
        ((v4f*)tile[rr])[cv] = v;
    }
    __syncthreads();

    for (int i = threadIdx.x; i < LROWS * W; i += 256) {
        int rr = i >> 7;          // / W
        int col = i & (W - 1);    // % W
        int tr = rr + 1;
        float cc = tile[tr][col];
        float up = tile[tr - 1][col];
        float dn = tile[tr + 1][col];
        float lf = 0.f, rt = 0.f, ul = 0.f, ur = 0.f, dl = 0.f, dr = 0.f;
        if (col > 0) {
            lf = tile[tr][col - 1];
            ul = tile[tr - 1][col - 1];
            dl = tile[tr + 1][col - 1];
        }
        if (col < W - 1) {
            rt = tile[tr][col + 1];
            ur = tile[tr - 1][col + 1];
            dr = tile[tr + 1][col + 1];
        }
        float res = 8.0f * cc - (up + dn + lf + rt + ul + ur + dl + dr);
        __builtin_nontemporal_store(res, &oc[(h0 + rr) * W + col]);
    }
}

extern "C" void kernel_launch(void* const* d_in, const int* in_sizes, int n_in,
                              void* d_out, int out_size, void* d_ws, size_t ws_size,
                              hipStream_t stream) {
    const float* x = (const float*)d_in[0];
    float* out = (float*)d_out;

    double* psum = (double*)d_ws;                           // 8192 doubles
    double* psq = psum + NPART;                             // 8192 doubles
    int* compact = (int*)(psq + NPART);                     // 416 ints
    float* thr = (float*)(compact + B * KSEL);              // 11 floats (pad to 8B ok)
    unsigned* pg = (unsigned*)(thr + 12);                   // 8192*11 uints

    init_thresholds<<<1, 64, 0, stream>>>(thr);
    score_copy_kernel<<<NPART, 256, 0, stream>>>(x, thr, psum, psq, pg, out);
    select_kernel<<<B, 256, 0, stream>>>(psum, psq, pg, compact);
    laplace_kernel<<<B * KSEL * PERCH, 256, 0, stream>>>(x, compact, out);
}